// Round 16
// baseline (138.384 us; speedup 1.0000x reference)
//
#include <hip/hip_runtime.h>
#include <hip/hip_bf16.h>

// GAT layer, N=8192, F_IN=256, F_OUT=64.
//  kA : role by bid. bid<8192 -> stream block: ONE adj row per block, 4 waves
//       each own an 8KB quarter-row; all 8 chunk-loads issued upfront (8KB in
//       flight/wave), ballots -> LDS (1KB), wave 0 does one coalesced 1KB
//       ML store. 32768 streaming waves total (4x R15).
//       bid>=8192 -> k1 block: 4 waves x 1 row (R13-proven body): scalar
//       Wh=h@W, Bpack bf16 B-frags, factors expg/expg2/Af/Cf/Enf.
//  k2b: U = adj@Wh from bitmask via MFMA; dual row-set; fragment prefetch.
//  k3 : fused softmax + attention@U + ELU; factorized weights; ones-fragment
//       MFMA denominator; fragment prefetch. (Both byte-identical to R15.)
//
// Fragment convention (proven rounds 1/3/4/5):
//  element e of lane l <-> k = kblock*32 + (l>>4)*8 + e; A row / B col = l&15;
//  C/D: col = l&15, row = (l>>4)*4 + reg.
//  Bpack/Upack: frag[(kb*4+b)*64 + lane][e]  (s16x8 per lane)
// Mask bit (row i, col j): word ML[i*128 + (j>>8)*4 + (j&3)], bit (j>>2)&63.

#define N 8192

typedef float f32x4 __attribute__((ext_vector_type(4)));
typedef short s16x8 __attribute__((ext_vector_type(8)));
typedef unsigned long long u64;
typedef u64 u64x2 __attribute__((ext_vector_type(2)));

union PF { s16x8 v; unsigned u[4]; };

__device__ __forceinline__ unsigned short f2bf(float x) {
  unsigned u = __float_as_uint(x);
  u += 0x7FFFu + ((u >> 16) & 1u);   // RNE
  return (unsigned short)(u >> 16);
}
__device__ __forceinline__ unsigned pack2(unsigned short lo, unsigned short hi) {
  return (unsigned)lo | ((unsigned)hi << 16);
}
// round-half-up bf16 pair pack (2 ops/elem; wt small positive => safe)
__device__ __forceinline__ unsigned packrn(float lo, float hi) {
  return ((__float_as_uint(lo) + 0x8000u) >> 16) |
         ((__float_as_uint(hi) + 0x8000u) & 0xFFFF0000u);
}

#define MFMA __builtin_amdgcn_mfma_f32_16x16x32_bf16

// ---------------- kA: 1-row stream blocks + k1 tail blocks ----------------
__global__ __launch_bounds__(256) void kA(const float* __restrict__ adj,
                                          const float* __restrict__ h,
                                          const float* __restrict__ W,
                                          const float* __restrict__ a,
                                          u64* __restrict__ ML,
                                          unsigned short* __restrict__ Bpack,
                                          float* __restrict__ expg,
                                          float* __restrict__ expg2,
                                          float* __restrict__ Af,
                                          float* __restrict__ Cf,
                                          float* __restrict__ Enf) {
  __shared__ u64 mbuf[128];   // 1 KB: one row's mask words
  const int l = threadIdx.x & 63;
  const int w = threadIdx.x >> 6;
  const int bid = blockIdx.x;
  if (bid < 8192) {
    // ----- stream block: one row, 4 waves x 8KB quarter-row -----
    const int i = bid;
    const float* ap = adj + (size_t)i * N + (w << 11) + (l << 2);
    // all 8 chunk loads in flight (8 KB/wave)
    f32x4 v0 = *(const f32x4*)(ap + (0 << 8));
    f32x4 v1 = *(const f32x4*)(ap + (1 << 8));
    f32x4 v2 = *(const f32x4*)(ap + (2 << 8));
    f32x4 v3 = *(const f32x4*)(ap + (3 << 8));
    f32x4 v4 = *(const f32x4*)(ap + (4 << 8));
    f32x4 v5 = *(const f32x4*)(ap + (5 << 8));
    f32x4 v6 = *(const f32x4*)(ap + (6 << 8));
    f32x4 v7 = *(const f32x4*)(ap + (7 << 8));
#define KCH(vk, c) {                                                      \
    u64 B0 = __ballot(vk.x > 0.f);                                        \
    u64 B1 = __ballot(vk.y > 0.f);                                        \
    u64 B2 = __ballot(vk.z > 0.f);                                        \
    u64 B3 = __ballot(vk.w > 0.f);                                        \
    if (l == 0) {                                                         \
      u64x2* q = (u64x2*)&mbuf[(w << 5) + ((c) << 2)];                    \
      u64x2 t0; t0.x = B0; t0.y = B1;                                     \
      u64x2 t1; t1.x = B2; t1.y = B3;                                     \
      q[0] = t0; q[1] = t1;                                               \
    } }
    KCH(v0, 0) KCH(v1, 1) KCH(v2, 2) KCH(v3, 3)
    KCH(v4, 4) KCH(v5, 5) KCH(v6, 6) KCH(v7, 7)
#undef KCH
    __syncthreads();
    if (w == 0) {
      u64x2 mv = *((const u64x2*)&mbuf[l << 1]);
      ((u64x2*)(ML + (size_t)i * 128))[l] = mv;   // one coalesced 1KB store
    }
  } else {
    // ----- k1 block: 4 waves x 1 row (R13-proven body) -----
    const int i = ((bid - 8192) << 2) + w;
    const float* hrow = h + (size_t)i * 256;
    float acc = 0.f;
#pragma unroll 4
    for (int kb = 0; kb < 64; ++kb) {
      f32x4 hv = *(const f32x4*)(hrow + (kb << 2));
      acc += hv.x * W[((kb << 2) + 0) * 64 + l];
      acc += hv.y * W[((kb << 2) + 1) * 64 + l];
      acc += hv.z * W[((kb << 2) + 2) * 64 + l];
      acc += hv.w * W[((kb << 2) + 3) * 64 + l];
    }
    float s1 = acc * a[l];
    float s2 = acc * a[64 + l];
#pragma unroll
    for (int d = 32; d > 0; d >>= 1) {
      s1 += __shfl_xor(s1, d);
      s2 += __shfl_xor(s2, d);
    }
    if (l == 0) {
      expg[i]  = __expf(s2);
      expg2[i] = __expf(0.2f * s2);
      Af[i]    = __expf(s1);
      Cf[i]    = __expf(0.2f * s1);
      Enf[i]   = __expf(-s1);
    }
    const int kb = i >> 5;
    const int b = l >> 4;
    const int lp = (l & 15) | (((i >> 3) & 3) << 4);
    const int e = i & 7;
    Bpack[(((size_t)(kb * 4 + b)) * 64 + lp) * 8 + e] = f2bf(acc);
  }
}

// ---------------- k2b: U from mask via MFMA, dual row-set, frag prefetch ----------------
__global__ __launch_bounds__(512) void k2b(const u64* __restrict__ ML,
                                           const unsigned short* __restrict__ Bpack,
                                           unsigned short* __restrict__ Upack) {
  __shared__ float red[2][8][64][16];   // 64 KB
  const int l = threadIdx.x & 63;
  const int w = threadIdx.x >> 6;
  const int i0 = blockIdx.x << 5;          // 32 rows/block
  const int r = l & 15, kg = l >> 4;
  const s16x8* Bv = (const s16x8*)Bpack;
  const u64x2* mrow0 = (const u64x2*)(ML + (size_t)(i0 + r) * 128);
  const u64x2* mrow1 = (const u64x2*)(ML + (size_t)(i0 + 16 + r) * 128);
  const int sh0 = kg << 1;
  f32x4 x0 = {0.f,0.f,0.f,0.f}, x1 = x0, x2 = x0, x3 = x0;
  f32x4 y0 = x0, y1 = x0, y2 = x0, y3 = x0;
  const int jb0 = w << 5;
  s16x8 c0, c1, c2, c3;
  {
    const size_t bi = ((size_t)jb0 << 8) + l;
    c0 = Bv[bi]; c1 = Bv[bi + 64]; c2 = Bv[bi + 128]; c3 = Bv[bi + 192];
  }
  for (int cc = 0; cc < 4; ++cc) {
    const int c = (w << 2) + cc;           // chunk of 256 cols
    u64x2 ma = mrow0[(c << 1)], mb = mrow0[(c << 1) + 1];
    const u64 xa0 = ma.x >> sh0, xa1 = ma.y >> sh0,
              xa2 = mb.x >> sh0, xa3 = mb.y >> sh0;
    u64x2 mc = mrow1[(c << 1)], md = mrow1[(c << 1) + 1];
    const u64 ya0 = mc.x >> sh0, ya1 = mc.y >> sh0,
              ya2 = md.x >> sh0, ya3 = md.y >> sh0;
#pragma unroll
    for (int j7 = 0; j7 < 8; ++j7) {
      const int jb = (c << 3) + j7;
      const int jbn = (cc == 3 && j7 == 7) ? jb : (jb + 1);
      const size_t bn = ((size_t)jbn << 8) + l;
      s16x8 n0 = Bv[bn], n1 = Bv[bn + 64], n2 = Bv[bn + 128], n3 = Bv[bn + 192];
      const unsigned p0 = (unsigned)(xa0 >> (j7 << 3)) & 1u;
      const unsigned p1 = (unsigned)(xa1 >> (j7 << 3)) & 1u;
      const unsigned p2 = (unsigned)(xa2 >> (j7 << 3)) & 1u;
      const unsigned p3 = (unsigned)(xa3 >> (j7 << 3)) & 1u;
      const unsigned p4 = (unsigned)(xa0 >> ((j7 << 3) + 1)) & 1u;
      const unsigned p5 = (unsigned)(xa1 >> ((j7 << 3) + 1)) & 1u;
      const unsigned p6 = (unsigned)(xa2 >> ((j7 << 3) + 1)) & 1u;
      const unsigned p7 = (unsigned)(xa3 >> ((j7 << 3) + 1)) & 1u;
      const unsigned q0 = (unsigned)(ya0 >> (j7 << 3)) & 1u;
      const unsigned q1 = (unsigned)(ya1 >> (j7 << 3)) & 1u;
      const unsigned q2 = (unsigned)(ya2 >> (j7 << 3)) & 1u;
      const unsigned q3 = (unsigned)(ya3 >> (j7 << 3)) & 1u;
      const unsigned q4 = (unsigned)(ya0 >> ((j7 << 3) + 1)) & 1u;
      const unsigned q5 = (unsigned)(ya1 >> ((j7 << 3) + 1)) & 1u;
      const unsigned q6 = (unsigned)(ya2 >> ((j7 << 3) + 1)) & 1u;
      const unsigned q7 = (unsigned)(ya3 >> ((j7 << 3) + 1)) & 1u;
      s16x8 af0, af1;
      af0[0] = p0 ? (short)0x3F80 : (short)0;
      af0[1] = p1 ? (short)0x3F80 : (short)0;
      af0[2] = p2 ? (short)0x3F80 : (short)0;
      af0[3] = p3 ? (short)0x3F80 : (short)0;
      af0[4] = p4 ? (short)0x3F80 : (short)0;
      af0[5] = p5 ? (short)0x3F80 : (short)0;
      af0[6] = p6 ? (short)0x3F80 : (short)0;
      af0[7] = p7 ? (short)0x3F80 : (short)0;
      af1[0] = q0 ? (short)0x3F80 : (short)0;
      af1[1] = q1 ? (short)0x3F80 : (short)0;
      af1[2] = q2 ? (short)0x3F80 : (short)0;
      af1[3] = q3 ? (short)0x3F80 : (short)0;
      af1[4] = q4 ? (short)0x3F80 : (short)0;
      af1[5] = q5 ? (short)0x3F80 : (short)0;
      af1[6] = q6 ? (short)0x3F80 : (short)0;
      af1[7] = q7 ? (short)0x3F80 : (short)0;
      x0 = MFMA(af0, c0, x0, 0, 0, 0);
      x1 = MFMA(af0, c1, x1, 0, 0, 0);
      x2 = MFMA(af0, c2, x2, 0, 0, 0);
      x3 = MFMA(af0, c3, x3, 0, 0, 0);
      y0 = MFMA(af1, c0, y0, 0, 0, 0);
      y1 = MFMA(af1, c1, y1, 0, 0, 0);
      y2 = MFMA(af1, c2, y2, 0, 0, 0);
      y3 = MFMA(af1, c3, y3, 0, 0, 0);
      c0 = n0; c1 = n1; c2 = n2; c3 = n3;
    }
  }
#pragma unroll
  for (int q = 0; q < 4; ++q) {
    red[0][w][l][q] = x0[q]; red[0][w][l][4 + q] = x1[q];
    red[0][w][l][8 + q] = x2[q]; red[0][w][l][12 + q] = x3[q];
    red[1][w][l][q] = y0[q]; red[1][w][l][4 + q] = y1[q];
    red[1][w][l][8 + q] = y2[q]; red[1][w][l][12 + q] = y3[q];
  }
  __syncthreads();
  const int tl = threadIdx.x & 63;
  const int b = (threadIdx.x >> 6) & 3;
  const int sE = threadIdx.x >> 8;
  const int reg0 = sE << 1;
#pragma unroll
  for (int s = 0; s < 2; ++s) {
    float u0 = 0.f, u1 = 0.f;
#pragma unroll
    for (int w8 = 0; w8 < 8; ++w8) {
      u0 += red[s][w8][tl][(b << 2) + reg0];
      u1 += red[s][w8][tl][(b << 2) + reg0 + 1];
    }
    const int k0 = i0 + (s << 4) + ((tl >> 4) << 2) + reg0;
    const unsigned pkv = pack2(f2bf(u0), f2bf(u1));
    const int kbD = k0 >> 5, lgrp = (k0 >> 3) & 3, e0 = k0 & 7;
    *(unsigned*)((char*)Upack +
        ((size_t)((kbD << 2) + b) * 64 + ((tl & 15) | (lgrp << 4))) * 16 + (e0 << 1)) = pkv;
  }
}

// ---------------- k3: fused softmax + attention@U + ELU, frag prefetch ----------------
__global__ __launch_bounds__(512) void k3(const u64* __restrict__ ML,
                                          const unsigned short* __restrict__ Upack,
                                          const float* __restrict__ expg,
                                          const float* __restrict__ expg2,
                                          const float* __restrict__ Af,
                                          const float* __restrict__ Cf,
                                          const float* __restrict__ Enf,
                                          float* __restrict__ out) {
  __shared__ float red[2][8][64][16];   // 64 KB
  __shared__ float wred[2][8][16];
  const int l = threadIdx.x & 63;
  const int w = threadIdx.x >> 6;
  const int i0 = blockIdx.x << 5;
  const int r = l & 15, kg = l >> 4;
  const float enf0 = Enf[i0 + r],      enf1 = Enf[i0 + 16 + r];
  const float Ar0 = Af[i0 + r],        Cr0 = Cf[i0 + r];
  const float Ar1 = Af[i0 + 16 + r],   Cr1 = Cf[i0 + 16 + r];
  const s16x8* Uv = (const s16x8*)Upack;
  const u64x2* mrow0 = (const u64x2*)(ML + (size_t)(i0 + r) * 128);
  const u64x2* mrow1 = (const u64x2*)(ML + (size_t)(i0 + 16 + r) * 128);
  const int sh0 = kg << 1;
  const s16x8 ones = {(short)0x3F80, (short)0x3F80, (short)0x3F80, (short)0x3F80,
                      (short)0x3F80, (short)0x3F80, (short)0x3F80, (short)0x3F80};
  f32x4 x0 = {0.f,0.f,0.f,0.f}, x1 = x0, x2 = x0, x3 = x0, xd = x0;
  f32x4 y0 = x0, y1 = x0, y2 = x0, y3 = x0, yd = x0;
  const int jb0 = w << 5;
  s16x8 c0, c1, c2, c3;
  {
    const size_t bi = ((size_t)jb0 << 8) + l;
    c0 = Uv[bi]; c1 = Uv[bi + 64]; c2 = Uv[bi + 128]; c3 = Uv[bi + 192];
  }
  for (int cc = 0; cc < 4; ++cc) {
    const int c = (w << 2) + cc;
    u64x2 ma = mrow0[(c << 1)], mb = mrow0[(c << 1) + 1];
    const u64 xa0 = ma.x >> sh0, xa1 = ma.y >> sh0,
              xa2 = mb.x >> sh0, xa3 = mb.y >> sh0;
    u64x2 mc = mrow1[(c << 1)], md = mrow1[(c << 1) + 1];
    const u64 ya0 = mc.x >> sh0, ya1 = mc.y >> sh0,
              ya2 = md.x >> sh0, ya3 = md.y >> sh0;
#pragma unroll
    for (int j7 = 0; j7 < 8; ++j7) {
      const int jb = (c << 3) + j7;
      const int jbn = (cc == 3 && j7 == 7) ? jb : (jb + 1);
      const size_t bn = ((size_t)jbn << 8) + l;
      s16x8 n0 = Uv[bn], n1 = Uv[bn + 64], n2 = Uv[bn + 128], n3 = Uv[bn + 192];
      f32x4 eg0 = *(const f32x4*)(expg + (jb << 5) + (kg << 3));
      f32x4 eg1 = *(const f32x4*)(expg + (jb << 5) + (kg << 3) + 4);
      f32x4 eh0 = *(const f32x4*)(expg2 + (jb << 5) + (kg << 3));
      f32x4 eh1 = *(const f32x4*)(expg2 + (jb << 5) + (kg << 3) + 4);
#define WT(wq, sh, egv, ehv, enf, Ar, Cr)                                    \
      ((((wq) >> (sh)) & 1ull) ?                                             \
        (((egv) > (enf)) ? (Ar) * (egv) : (Cr) * (ehv)) : 0.f)
      const float w00 = WT(xa0, (j7 << 3),     eg0.x, eh0.x, enf0, Ar0, Cr0);
      const float w01 = WT(xa1, (j7 << 3),     eg0.y, eh0.y, enf0, Ar0, Cr0);
      const float w02 = WT(xa2, (j7 << 3),     eg0.z, eh0.z, enf0, Ar0, Cr0);
      const float w03 = WT(xa3, (j7 << 3),     eg0.w, eh0.w, enf0, Ar0, Cr0);
      const float w04 = WT(xa0, (j7 << 3) + 1, eg1.x, eh1.x, enf0, Ar0, Cr0);
      const float w05 = WT(xa1, (j7 << 3) + 1, eg1.y, eh1.y, enf0, Ar0, Cr0);
      const float w06 = WT(xa2, (j7 << 3) + 1, eg1.z, eh1.z, enf0, Ar0, Cr0);
      const float w07 = WT(xa3, (j7 << 3) + 1, eg1.w, eh1.w, enf0, Ar0, Cr0);
      const float w10 = WT(ya0, (j7 << 3),     eg0.x, eh0.x, enf1, Ar1, Cr1);
      const float w11 = WT(ya1, (j7 << 3),     eg0.y, eh0.y, enf1, Ar1, Cr1);
      const float w12 = WT(ya2, (j7 << 3),     eg0.z, eh0.z, enf1, Ar1, Cr1);
      const float w13 = WT(ya3, (j7 << 3),     eg0.w, eh0.w, enf1, Ar1, Cr1);
      const float w14 = WT(ya0, (j7 << 3) + 1, eg1.x, eh1.x, enf1, Ar1, Cr1);
      const float w15 = WT(ya1, (j7 << 3) + 1, eg1.y, eh1.y, enf1, Ar1, Cr1);
      const float w16 = WT(ya2, (j7 << 3) + 1, eg1.z, eh1.z, enf1, Ar1, Cr1);
      const float w17 = WT(ya3, (j7 << 3) + 1, eg1.w, eh1.w, enf1, Ar1, Cr1);
#undef WT
      PF pf0, pf1;
      pf0.u[0] = packrn(w00, w01); pf0.u[1] = packrn(w02, w03);
      pf0.u[2] = packrn(w04, w05); pf0.u[3] = packrn(w06, w07);
      pf1.u[0] = packrn(w10, w11); pf1.u[1] = packrn(w12, w13);
      pf1.u[2] = packrn(w14, w15); pf1.u[3] = packrn(w16, w17);
      x0 = MFMA(pf0.v, c0, x0, 0, 0, 0);
      x1 = MFMA(pf0.v, c1, x1, 0, 0, 0);
      x2 = MFMA(pf0.v, c2, x2, 0, 0, 0);
      x3 = MFMA(pf0.v, c3, x3, 0, 0, 0);
      xd = MFMA(pf0.v, ones, xd, 0, 0, 0);
      y0 = MFMA(pf1.v, c0, y0, 0, 0, 0);
      y1 = MFMA(pf1.v, c1, y1, 0, 0, 0);
      y2 = MFMA(pf1.v, c2, y2, 0, 0, 0);
      y3 = MFMA(pf1.v, c3, y3, 0, 0, 0);
      yd = MFMA(pf1.v, ones, yd, 0, 0, 0);
      c0 = n0; c1 = n1; c2 = n2; c3 = n3;
    }
  }
  if (r == 0) {
#pragma unroll
    for (int q = 0; q < 4; ++q) {
      wred[0][w][(kg << 2) + q] = xd[q];   // rowsum (all cols of ones-D equal)
      wred[1][w][(kg << 2) + q] = yd[q];
    }
  }
#pragma unroll
  for (int q = 0; q < 4; ++q) {
    red[0][w][l][q] = x0[q]; red[0][w][l][4 + q] = x1[q];
    red[0][w][l][8 + q] = x2[q]; red[0][w][l][12 + q] = x3[q];
    red[1][w][l][q] = y0[q]; red[1][w][l][4 + q] = y1[q];
    red[1][w][l][8 + q] = y2[q]; red[1][w][l][12 + q] = y3[q];
  }
  __syncthreads();
  const int tl = threadIdx.x & 63;
  const int b = (threadIdx.x >> 6) & 3;
  const int sE = threadIdx.x >> 8;
#pragma unroll
  for (int s = 0; s < 2; ++s) {
#pragma unroll
    for (int q = 0; q < 2; ++q) {
      const int reg = (sE << 1) + q;
      const int idx = (b << 2) + reg;
      const int row = ((tl >> 4) << 2) + reg;
      float sv = 0.f, dv = 0.f;
#pragma unroll
      for (int w8 = 0; w8 < 8; ++w8) {
        sv += red[s][w8][tl][idx];
        dv += wred[s][w8][row];
      }
      dv = (dv > 0.f) ? dv : 1.f;            // defensive: avoid 0/0
      float v = sv / dv;
      v = (v > 0.f) ? v : (__expf(v) - 1.f); // ELU
      out[(size_t)(i0 + (s << 4) + row) * 64 + (b << 4) + (tl & 15)] = v;
    }
  }
}

extern "C" void kernel_launch(void* const* d_in, const int* in_sizes, int n_in,
                              void* d_out, int out_size, void* d_ws, size_t ws_size,
                              hipStream_t stream) {
  const float* h   = (const float*)d_in[0];
  const float* adj = (const float*)d_in[1];
  const float* W   = (const float*)d_in[2];
  const float* a   = (const float*)d_in[3];
  float* out = (float*)d_out;
  char* ws = (char*)d_ws;
  unsigned short* Bpack = (unsigned short*)(ws);                   // 1 MB
  unsigned short* Upack = (unsigned short*)(ws + (1u << 20));      // 1 MB
  float* expg  = (float*)(ws + (2u << 20));                        // 32 KB
  float* expg2 = (float*)(ws + (2u << 20) + 1u * 32768u);          // 32 KB
  float* Af    = (float*)(ws + (2u << 20) + 2u * 32768u);          // 32 KB
  float* Cf    = (float*)(ws + (2u << 20) + 3u * 32768u);          // 32 KB
  float* Enf   = (float*)(ws + (2u << 20) + 4u * 32768u);          // 32 KB
  u64* ML = (u64*)(ws + (3u << 20));                               // 8 MB

  hipLaunchKernelGGL(kA,  dim3(10240), dim3(256), 0, stream,
                     adj, h, W, a, ML, Bpack, expg, expg2, Af, Cf, Enf);
  hipLaunchKernelGGL(k2b, dim3(256), dim3(512), 0, stream,
                     ML, Bpack, Upack);
  hipLaunchKernelGGL(k3,  dim3(256), dim3(512), 0, stream,
                     ML, Upack, expg, expg2, Af, Cf, Enf, out);
}

// Round 17
// 117.147 us; speedup vs baseline: 1.1813x; 1.1813x over previous
//
#include <hip/hip_runtime.h>
#include <hip/hip_bf16.h>

// GAT layer, N=8192, F_IN=256, F_OUT=64.
//  kA : R15-proven: waves 0,1 -> adj mask stream (rows 2b,2b+1): depth-2
//       register pipeline (8KB in flight), ballots -> LDS (1KB/row), ONE
//       coalesced 1KB wave-store per row. wave 2 -> k1 both rows (shared W
//       loads); wave 3 idle. ML[i][c][q] bit l = adj[i][c*256+l*4+q] > 0.
//  k2b: U = adj@Wh from bitmask via MFMA; dual row-set; fragment loads
//       register-prefetched TWO jb ahead (depth-2; L2 latency ~200cyc >
//       one jb-step of work).
//  k3 : fused softmax + attention@U + ELU; factorized weights; ones-fragment
//       MFMA denominator; depth-2 fragment prefetch.
//
// Fragment convention (proven rounds 1/3/4/5):
//  element e of lane l <-> k = kblock*32 + (l>>4)*8 + e; A row / B col = l&15;
//  C/D: col = l&15, row = (l>>4)*4 + reg.
//  Bpack/Upack: frag[(kb*4+b)*64 + lane][e]  (s16x8 per lane)
// Mask bit (row i, col j): word ML[i*128 + (j>>8)*4 + (j&3)], bit (j>>2)&63.

#define N 8192

typedef float f32x4 __attribute__((ext_vector_type(4)));
typedef short s16x8 __attribute__((ext_vector_type(8)));
typedef unsigned long long u64;
typedef u64 u64x2 __attribute__((ext_vector_type(2)));

union PF { s16x8 v; unsigned u[4]; };

__device__ __forceinline__ unsigned short f2bf(float x) {
  unsigned u = __float_as_uint(x);
  u += 0x7FFFu + ((u >> 16) & 1u);   // RNE
  return (unsigned short)(u >> 16);
}
__device__ __forceinline__ unsigned pack2(unsigned short lo, unsigned short hi) {
  return (unsigned)lo | ((unsigned)hi << 16);
}
// round-half-up bf16 pair pack (2 ops/elem; wt small positive => safe)
__device__ __forceinline__ unsigned packrn(float lo, float hi) {
  return ((__float_as_uint(lo) + 0x8000u) >> 16) |
         ((__float_as_uint(hi) + 0x8000u) & 0xFFFF0000u);
}

#define MFMA __builtin_amdgcn_mfma_f32_16x16x32_bf16

// ---------------- kA: mask stream (LDS-staged, depth-2) + 2-row k1 (R15) ----------------
__global__ __launch_bounds__(256) void kA(const float* __restrict__ adj,
                                          const float* __restrict__ h,
                                          const float* __restrict__ W,
                                          const float* __restrict__ a,
                                          u64* __restrict__ ML,
                                          unsigned short* __restrict__ Bpack,
                                          float* __restrict__ expg,
                                          float* __restrict__ expg2,
                                          float* __restrict__ Af,
                                          float* __restrict__ Cf,
                                          float* __restrict__ Enf) {
  __shared__ u64 mbuf[2][128];   // 2 KB: per-streaming-wave mask staging
  const int l = threadIdx.x & 63;
  const int w = threadIdx.x >> 6;
  const int bid = blockIdx.x;
  if (w < 2) {
    const int i = (bid << 1) + w;
    const float* ap = adj + (size_t)i * N + (l << 2);
    u64* mp = ML + (size_t)i * 128;
    f32x4 a0 = *(const f32x4*)(ap + (0 << 8));
    f32x4 a1 = *(const f32x4*)(ap + (1 << 8));
    f32x4 a2 = *(const f32x4*)(ap + (2 << 8));
    f32x4 a3 = *(const f32x4*)(ap + (3 << 8));
    f32x4 b0 = *(const f32x4*)(ap + (4 << 8));
    f32x4 b1 = *(const f32x4*)(ap + (5 << 8));
    f32x4 b2 = *(const f32x4*)(ap + (6 << 8));
    f32x4 b3 = *(const f32x4*)(ap + (7 << 8));
    for (int it = 0; it < 8; ++it) {
      const int gn = (it < 6) ? (it + 2) : it;   // tail: L2-hot reload
      f32x4 n0 = *(const f32x4*)(ap + (((gn << 2) + 0) << 8));
      f32x4 n1 = *(const f32x4*)(ap + (((gn << 2) + 1) << 8));
      f32x4 n2 = *(const f32x4*)(ap + (((gn << 2) + 2) << 8));
      f32x4 n3 = *(const f32x4*)(ap + (((gn << 2) + 3) << 8));
      u64 B0  = __ballot(a0.x > 0.f), B1  = __ballot(a0.y > 0.f);
      u64 B2  = __ballot(a0.z > 0.f), B3  = __ballot(a0.w > 0.f);
      u64 B4  = __ballot(a1.x > 0.f), B5  = __ballot(a1.y > 0.f);
      u64 B6  = __ballot(a1.z > 0.f), B7  = __ballot(a1.w > 0.f);
      u64 B8  = __ballot(a2.x > 0.f), B9  = __ballot(a2.y > 0.f);
      u64 B10 = __ballot(a2.z > 0.f), B11 = __ballot(a2.w > 0.f);
      u64 B12 = __ballot(a3.x > 0.f), B13 = __ballot(a3.y > 0.f);
      u64 B14 = __ballot(a3.z > 0.f), B15 = __ballot(a3.w > 0.f);
      if (l == 0) {
        u64x2* q = (u64x2*)&mbuf[w][it << 4];
        u64x2 t0; t0.x = B0;  t0.y = B1;  q[0] = t0;
        u64x2 t1; t1.x = B2;  t1.y = B3;  q[1] = t1;
        u64x2 t2; t2.x = B4;  t2.y = B5;  q[2] = t2;
        u64x2 t3; t3.x = B6;  t3.y = B7;  q[3] = t3;
        u64x2 t4; t4.x = B8;  t4.y = B9;  q[4] = t4;
        u64x2 t5; t5.x = B10; t5.y = B11; q[5] = t5;
        u64x2 t6; t6.x = B12; t6.y = B13; q[6] = t6;
        u64x2 t7; t7.x = B14; t7.y = B15; q[7] = t7;
      }
      a0 = b0; a1 = b1; a2 = b2; a3 = b3;
      b0 = n0; b1 = n1; b2 = n2; b3 = n3;
    }
    asm volatile("s_waitcnt lgkmcnt(0)" ::: "memory");
    u64x2 mv = *((const u64x2*)&mbuf[w][l << 1]);
    ((u64x2*)mp)[l] = mv;                      // one coalesced 1KB store/row
  } else if (w == 2) {
    const int i0r = bid << 1;
    const float* h0 = h + (size_t)i0r * 256;
    const float* h1 = h0 + 256;
    float acc0 = 0.f, acc1 = 0.f;
#pragma unroll 4
    for (int kb = 0; kb < 64; ++kb) {
      f32x4 hv0 = *(const f32x4*)(h0 + (kb << 2));
      f32x4 hv1 = *(const f32x4*)(h1 + (kb << 2));
      const float w0 = W[((kb << 2) + 0) * 64 + l];
      const float w1 = W[((kb << 2) + 1) * 64 + l];
      const float w2 = W[((kb << 2) + 2) * 64 + l];
      const float w3 = W[((kb << 2) + 3) * 64 + l];
      acc0 += hv0.x * w0; acc0 += hv0.y * w1;
      acc0 += hv0.z * w2; acc0 += hv0.w * w3;
      acc1 += hv1.x * w0; acc1 += hv1.y * w1;
      acc1 += hv1.z * w2; acc1 += hv1.w * w3;
    }
    const float al = a[l], bl = a[64 + l];
    float s10 = acc0 * al, s20 = acc0 * bl;
    float s11 = acc1 * al, s21 = acc1 * bl;
#pragma unroll
    for (int d = 32; d > 0; d >>= 1) {
      s10 += __shfl_xor(s10, d);
      s20 += __shfl_xor(s20, d);
      s11 += __shfl_xor(s11, d);
      s21 += __shfl_xor(s21, d);
    }
    if (l == 0) {
      expg[i0r]  = __expf(s20);
      expg2[i0r] = __expf(0.2f * s20);
      Af[i0r]    = __expf(s10);
      Cf[i0r]    = __expf(0.2f * s10);
      Enf[i0r]   = __expf(-s10);
      expg[i0r + 1]  = __expf(s21);
      expg2[i0r + 1] = __expf(0.2f * s21);
      Af[i0r + 1]    = __expf(s11);
      Cf[i0r + 1]    = __expf(0.2f * s11);
      Enf[i0r + 1]   = __expf(-s11);
    }
#pragma unroll
    for (int rr = 0; rr < 2; ++rr) {
      const int i = i0r + rr;
      const float acc = rr ? acc1 : acc0;
      const int kb = i >> 5;
      const int b = l >> 4;
      const int lp = (l & 15) | (((i >> 3) & 3) << 4);
      const int e = i & 7;
      Bpack[(((size_t)(kb * 4 + b)) * 64 + lp) * 8 + e] = f2bf(acc);
    }
  }
  // w == 3: idle
}

// ---------------- k2b: U from mask via MFMA, dual row-set, depth-2 prefetch ----------------
__global__ __launch_bounds__(512) void k2b(const u64* __restrict__ ML,
                                           const unsigned short* __restrict__ Bpack,
                                           unsigned short* __restrict__ Upack) {
  __shared__ float red[2][8][64][16];   // 64 KB
  const int l = threadIdx.x & 63;
  const int w = threadIdx.x >> 6;
  const int i0 = blockIdx.x << 5;          // 32 rows/block
  const int r = l & 15, kg = l >> 4;
  const s16x8* Bv = (const s16x8*)Bpack;
  const u64x2* mrow0 = (const u64x2*)(ML + (size_t)(i0 + r) * 128);
  const u64x2* mrow1 = (const u64x2*)(ML + (size_t)(i0 + 16 + r) * 128);
  const int sh0 = kg << 1;
  f32x4 x0 = {0.f,0.f,0.f,0.f}, x1 = x0, x2 = x0, x3 = x0;
  f32x4 y0 = x0, y1 = x0, y2 = x0, y3 = x0;
  const int jb0 = w << 5;
  s16x8 c0, c1, c2, c3, d0, d1, d2, d3;
  {
    const size_t bi = ((size_t)jb0 << 8) + l;
    c0 = Bv[bi]; c1 = Bv[bi + 64]; c2 = Bv[bi + 128]; c3 = Bv[bi + 192];
    const size_t bj = ((size_t)(jb0 + 1) << 8) + l;
    d0 = Bv[bj]; d1 = Bv[bj + 64]; d2 = Bv[bj + 128]; d3 = Bv[bj + 192];
  }
  for (int cc = 0; cc < 4; ++cc) {
    const int c = (w << 2) + cc;           // chunk of 256 cols
    u64x2 ma = mrow0[(c << 1)], mb = mrow0[(c << 1) + 1];
    const u64 xa0 = ma.x >> sh0, xa1 = ma.y >> sh0,
              xa2 = mb.x >> sh0, xa3 = mb.y >> sh0;
    u64x2 mc = mrow1[(c << 1)], md = mrow1[(c << 1) + 1];
    const u64 ya0 = mc.x >> sh0, ya1 = mc.y >> sh0,
              ya2 = md.x >> sh0, ya3 = md.y >> sh0;
#pragma unroll
    for (int j7 = 0; j7 < 8; ++j7) {
      const int jb = (c << 3) + j7;
      const int jbn = (cc == 3 && j7 >= 6) ? (jb0 + 31) : (jb + 2);
      const size_t bn = ((size_t)jbn << 8) + l;
      s16x8 n0 = Bv[bn], n1 = Bv[bn + 64], n2 = Bv[bn + 128], n3 = Bv[bn + 192];
      const unsigned p0 = (unsigned)(xa0 >> (j7 << 3)) & 1u;
      const unsigned p1 = (unsigned)(xa1 >> (j7 << 3)) & 1u;
      const unsigned p2 = (unsigned)(xa2 >> (j7 << 3)) & 1u;
      const unsigned p3 = (unsigned)(xa3 >> (j7 << 3)) & 1u;
      const unsigned p4 = (unsigned)(xa0 >> ((j7 << 3) + 1)) & 1u;
      const unsigned p5 = (unsigned)(xa1 >> ((j7 << 3) + 1)) & 1u;
      const unsigned p6 = (unsigned)(xa2 >> ((j7 << 3) + 1)) & 1u;
      const unsigned p7 = (unsigned)(xa3 >> ((j7 << 3) + 1)) & 1u;
      const unsigned q0 = (unsigned)(ya0 >> (j7 << 3)) & 1u;
      const unsigned q1 = (unsigned)(ya1 >> (j7 << 3)) & 1u;
      const unsigned q2 = (unsigned)(ya2 >> (j7 << 3)) & 1u;
      const unsigned q3 = (unsigned)(ya3 >> (j7 << 3)) & 1u;
      const unsigned q4 = (unsigned)(ya0 >> ((j7 << 3) + 1)) & 1u;
      const unsigned q5 = (unsigned)(ya1 >> ((j7 << 3) + 1)) & 1u;
      const unsigned q6 = (unsigned)(ya2 >> ((j7 << 3) + 1)) & 1u;
      const unsigned q7 = (unsigned)(ya3 >> ((j7 << 3) + 1)) & 1u;
      s16x8 af0, af1;
      af0[0] = p0 ? (short)0x3F80 : (short)0;
      af0[1] = p1 ? (short)0x3F80 : (short)0;
      af0[2] = p2 ? (short)0x3F80 : (short)0;
      af0[3] = p3 ? (short)0x3F80 : (short)0;
      af0[4] = p4 ? (short)0x3F80 : (short)0;
      af0[5] = p5 ? (short)0x3F80 : (short)0;
      af0[6] = p6 ? (short)0x3F80 : (short)0;
      af0[7] = p7 ? (short)0x3F80 : (short)0;
      af1[0] = q0 ? (short)0x3F80 : (short)0;
      af1[1] = q1 ? (short)0x3F80 : (short)0;
      af1[2] = q2 ? (short)0x3F80 : (short)0;
      af1[3] = q3 ? (short)0x3F80 : (short)0;
      af1[4] = q4 ? (short)0x3F80 : (short)0;
      af1[5] = q5 ? (short)0x3F80 : (short)0;
      af1[6] = q6 ? (short)0x3F80 : (short)0;
      af1[7] = q7 ? (short)0x3F80 : (short)0;
      x0 = MFMA(af0, c0, x0, 0, 0, 0);
      x1 = MFMA(af0, c1, x1, 0, 0, 0);
      x2 = MFMA(af0, c2, x2, 0, 0, 0);
      x3 = MFMA(af0, c3, x3, 0, 0, 0);
      y0 = MFMA(af1, c0, y0, 0, 0, 0);
      y1 = MFMA(af1, c1, y1, 0, 0, 0);
      y2 = MFMA(af1, c2, y2, 0, 0, 0);
      y3 = MFMA(af1, c3, y3, 0, 0, 0);
      c0 = d0; c1 = d1; c2 = d2; c3 = d3;
      d0 = n0; d1 = n1; d2 = n2; d3 = n3;
    }
  }
#pragma unroll
  for (int q = 0; q < 4; ++q) {
    red[0][w][l][q] = x0[q]; red[0][w][l][4 + q] = x1[q];
    red[0][w][l][8 + q] = x2[q]; red[0][w][l][12 + q] = x3[q];
    red[1][w][l][q] = y0[q]; red[1][w][l][4 + q] = y1[q];
    red[1][w][l][8 + q] = y2[q]; red[1][w][l][12 + q] = y3[q];
  }
  __syncthreads();
  const int tl = threadIdx.x & 63;
  const int b = (threadIdx.x >> 6) & 3;
  const int sE = threadIdx.x >> 8;
  const int reg0 = sE << 1;
#pragma unroll
  for (int s = 0; s < 2; ++s) {
    float u0 = 0.f, u1 = 0.f;
#pragma unroll
    for (int w8 = 0; w8 < 8; ++w8) {
      u0 += red[s][w8][tl][(b << 2) + reg0];
      u1 += red[s][w8][tl][(b << 2) + reg0 + 1];
    }
    const int k0 = i0 + (s << 4) + ((tl >> 4) << 2) + reg0;
    const unsigned pkv = pack2(f2bf(u0), f2bf(u1));
    const int kbD = k0 >> 5, lgrp = (k0 >> 3) & 3, e0 = k0 & 7;
    *(unsigned*)((char*)Upack +
        ((size_t)((kbD << 2) + b) * 64 + ((tl & 15) | (lgrp << 4))) * 16 + (e0 << 1)) = pkv;
  }
}

// ---------------- k3: fused softmax + attention@U + ELU, depth-2 prefetch ----------------
__global__ __launch_bounds__(512) void k3(const u64* __restrict__ ML,
                                          const unsigned short* __restrict__ Upack,
                                          const float* __restrict__ expg,
                                          const float* __restrict__ expg2,
                                          const float* __restrict__ Af,
                                          const float* __restrict__ Cf,
                                          const float* __restrict__ Enf,
                                          float* __restrict__ out) {
  __shared__ float red[2][8][64][16];   // 64 KB
  __shared__ float wred[2][8][16];
  const int l = threadIdx.x & 63;
  const int w = threadIdx.x >> 6;
  const int i0 = blockIdx.x << 5;
  const int r = l & 15, kg = l >> 4;
  const float enf0 = Enf[i0 + r],      enf1 = Enf[i0 + 16 + r];
  const float Ar0 = Af[i0 + r],        Cr0 = Cf[i0 + r];
  const float Ar1 = Af[i0 + 16 + r],   Cr1 = Cf[i0 + 16 + r];
  const s16x8* Uv = (const s16x8*)Upack;
  const u64x2* mrow0 = (const u64x2*)(ML + (size_t)(i0 + r) * 128);
  const u64x2* mrow1 = (const u64x2*)(ML + (size_t)(i0 + 16 + r) * 128);
  const int sh0 = kg << 1;
  const s16x8 ones = {(short)0x3F80, (short)0x3F80, (short)0x3F80, (short)0x3F80,
                      (short)0x3F80, (short)0x3F80, (short)0x3F80, (short)0x3F80};
  f32x4 x0 = {0.f,0.f,0.f,0.f}, x1 = x0, x2 = x0, x3 = x0, xd = x0;
  f32x4 y0 = x0, y1 = x0, y2 = x0, y3 = x0, yd = x0;
  const int jb0 = w << 5;
  s16x8 c0, c1, c2, c3, d0, d1, d2, d3;
  {
    const size_t bi = ((size_t)jb0 << 8) + l;
    c0 = Uv[bi]; c1 = Uv[bi + 64]; c2 = Uv[bi + 128]; c3 = Uv[bi + 192];
    const size_t bj = ((size_t)(jb0 + 1) << 8) + l;
    d0 = Uv[bj]; d1 = Uv[bj + 64]; d2 = Uv[bj + 128]; d3 = Uv[bj + 192];
  }
  for (int cc = 0; cc < 4; ++cc) {
    const int c = (w << 2) + cc;
    u64x2 ma = mrow0[(c << 1)], mb = mrow0[(c << 1) + 1];
    const u64 xa0 = ma.x >> sh0, xa1 = ma.y >> sh0,
              xa2 = mb.x >> sh0, xa3 = mb.y >> sh0;
    u64x2 mc = mrow1[(c << 1)], md = mrow1[(c << 1) + 1];
    const u64 ya0 = mc.x >> sh0, ya1 = mc.y >> sh0,
              ya2 = md.x >> sh0, ya3 = md.y >> sh0;
#pragma unroll
    for (int j7 = 0; j7 < 8; ++j7) {
      const int jb = (c << 3) + j7;
      const int jbn = (cc == 3 && j7 >= 6) ? (jb0 + 31) : (jb + 2);
      const size_t bn = ((size_t)jbn << 8) + l;
      s16x8 n0 = Uv[bn], n1 = Uv[bn + 64], n2 = Uv[bn + 128], n3 = Uv[bn + 192];
      f32x4 eg0 = *(const f32x4*)(expg + (jb << 5) + (kg << 3));
      f32x4 eg1 = *(const f32x4*)(expg + (jb << 5) + (kg << 3) + 4);
      f32x4 eh0 = *(const f32x4*)(expg2 + (jb << 5) + (kg << 3));
      f32x4 eh1 = *(const f32x4*)(expg2 + (jb << 5) + (kg << 3) + 4);
#define WT(wq, sh, egv, ehv, enf, Ar, Cr)                                    \
      ((((wq) >> (sh)) & 1ull) ?                                             \
        (((egv) > (enf)) ? (Ar) * (egv) : (Cr) * (ehv)) : 0.f)
      const float w00 = WT(xa0, (j7 << 3),     eg0.x, eh0.x, enf0, Ar0, Cr0);
      const float w01 = WT(xa1, (j7 << 3),     eg0.y, eh0.y, enf0, Ar0, Cr0);
      const float w02 = WT(xa2, (j7 << 3),     eg0.z, eh0.z, enf0, Ar0, Cr0);
      const float w03 = WT(xa3, (j7 << 3),     eg0.w, eh0.w, enf0, Ar0, Cr0);
      const float w04 = WT(xa0, (j7 << 3) + 1, eg1.x, eh1.x, enf0, Ar0, Cr0);
      const float w05 = WT(xa1, (j7 << 3) + 1, eg1.y, eh1.y, enf0, Ar0, Cr0);
      const float w06 = WT(xa2, (j7 << 3) + 1, eg1.z, eh1.z, enf0, Ar0, Cr0);
      const float w07 = WT(xa3, (j7 << 3) + 1, eg1.w, eh1.w, enf0, Ar0, Cr0);
      const float w10 = WT(ya0, (j7 << 3),     eg0.x, eh0.x, enf1, Ar1, Cr1);
      const float w11 = WT(ya1, (j7 << 3),     eg0.y, eh0.y, enf1, Ar1, Cr1);
      const float w12 = WT(ya2, (j7 << 3),     eg0.z, eh0.z, enf1, Ar1, Cr1);
      const float w13 = WT(ya3, (j7 << 3),     eg0.w, eh0.w, enf1, Ar1, Cr1);
      const float w14 = WT(ya0, (j7 << 3) + 1, eg1.x, eh1.x, enf1, Ar1, Cr1);
      const float w15 = WT(ya1, (j7 << 3) + 1, eg1.y, eh1.y, enf1, Ar1, Cr1);
      const float w16 = WT(ya2, (j7 << 3) + 1, eg1.z, eh1.z, enf1, Ar1, Cr1);
      const float w17 = WT(ya3, (j7 << 3) + 1, eg1.w, eh1.w, enf1, Ar1, Cr1);
#undef WT
      PF pf0, pf1;
      pf0.u[0] = packrn(w00, w01); pf0.u[1] = packrn(w02, w03);
      pf0.u[2] = packrn(w04, w05); pf0.u[3] = packrn(w06, w07);
      pf1.u[0] = packrn(w10, w11); pf1.u[1] = packrn(w12, w13);
      pf1.u[2] = packrn(w14, w15); pf1.u[3] = packrn(w16, w17);
      x0 = MFMA(pf0.v, c0, x0, 0, 0, 0);
      x1 = MFMA(pf0.v, c1, x1, 0, 0, 0);
      x2 = MFMA(pf0.v, c2, x2, 0, 0, 0);
      x3 = MFMA(pf0.v, c3, x3, 0, 0, 0);
      xd = MFMA(pf0.v, ones, xd, 0, 0, 0);
      y0 = MFMA(pf1.v, c0, y0, 0, 0, 0);
      y1 = MFMA(pf1.v, c1, y1, 0, 0, 0);
      y2 = MFMA(pf1.v, c2, y2, 0, 0, 0);
      y3 = MFMA(pf1.v, c3, y3, 0, 0, 0);
      yd = MFMA(pf1.v, ones, yd, 0, 0, 0);
      c0 = d0; c1 = d1; c2 = d2; c3 = d3;
      d0 = n0; d1 = n1; d2 = n2; d3 = n3;
    }
  }
  if (r == 0) {
#pragma unroll
    for (int q = 0; q < 4; ++q) {
      wred[0][w][(kg << 2) + q] = xd[q];   // rowsum (all cols of ones-D equal)
      wred[1][w][(kg << 2) + q] = yd[q];
    }
  }
#pragma unroll
  for (int q = 0; q < 4; ++q) {
    red[0][w][l][q] = x0[q]; red[0][w][l][4 + q] = x1[q];
    red[0][w][l][8 + q] = x2[q]; red[0][w][l][12 + q] = x3[q];
    red[1][w][l][q] = y0[q]; red[1][w][l][4 + q] = y1[q];
    red[1][w][l][8 + q] = y2[q]; red[1][w][l][12 + q] = y3[q];
  }
  __syncthreads();
  const int tl = threadIdx.x & 63;
  const int b = (threadIdx.x >> 6) & 3;
  const int sE = threadIdx.x >> 8;
#pragma unroll
  for (int s = 0; s < 2; ++s) {
#pragma unroll
    for (int q = 0; q < 2; ++q) {
      const int reg = (sE << 1) + q;
      const int idx = (b << 2) + reg;
      const int row = ((tl >> 4) << 2) + reg;
      float sv = 0.f, dv = 0.f;
#pragma unroll
      for (int w8 = 0; w8 < 8; ++w8) {
        sv += red[s][w8][tl][idx];
        dv += wred[s][w8][row];
      }
      dv = (dv > 0.f) ? dv : 1.f;            // defensive: avoid 0/0
      float v = sv / dv;
      v = (v > 0.f) ? v : (__expf(v) - 1.f); // ELU
      out[(size_t)(i0 + (s << 4) + row) * 64 + (b << 4) + (tl & 15)] = v;
    }
  }
}

extern "C" void kernel_launch(void* const* d_in, const int* in_sizes, int n_in,
                              void* d_out, int out_size, void* d_ws, size_t ws_size,
                              hipStream_t stream) {
  const float* h   = (const float*)d_in[0];
  const float* adj = (const float*)d_in[1];
  const float* W   = (const float*)d_in[2];
  const float* a   = (const float*)d_in[3];
  float* out = (float*)d_out;
  char* ws = (char*)d_ws;
  unsigned short* Bpack = (unsigned short*)(ws);                   // 1 MB
  unsigned short* Upack = (unsigned short*)(ws + (1u << 20));      // 1 MB
  float* expg  = (float*)(ws + (2u << 20));                        // 32 KB
  float* expg2 = (float*)(ws + (2u << 20) + 1u * 32768u);          // 32 KB
  float* Af    = (float*)(ws + (2u << 20) + 2u * 32768u);          // 32 KB
  float* Cf    = (float*)(ws + (2u << 20) + 3u * 32768u);          // 32 KB
  float* Enf   = (float*)(ws + (2u << 20) + 4u * 32768u);          // 32 KB
  u64* ML = (u64*)(ws + (3u << 20));                               // 8 MB

  hipLaunchKernelGGL(kA,  dim3(4096), dim3(256), 0, stream,
                     adj, h, W, a, ML, Bpack, expg, expg2, Af, Cf, Enf);
  hipLaunchKernelGGL(k2b, dim3(256), dim3(512), 0, stream,
                     ML, Bpack, Upack);
  hipLaunchKernelGGL(k3,  dim3(256), dim3(512), 0, stream,
                     ML, Upack, expg, expg2, Af, Cf, Enf, out);
}

// Round 18
// 114.448 us; speedup vs baseline: 1.2091x; 1.0236x over previous
//
#include <hip/hip_runtime.h>
#include <hip/hip_bf16.h>

// GAT layer, N=8192, F_IN=256, F_OUT=64.
//  kA : R15-proven bodies, 192-thread blocks (no idle wave): waves 0,1 ->
//       adj mask stream (rows 2b,2b+1): depth-2 register pipeline (8KB in
//       flight), ballots -> LDS (1KB/row), ONE coalesced 1KB store per row.
//       wave 2 -> k1 both rows (shared W loads).
//       ML[i][c][q] bit l = adj[i][c*256+l*4+q] > 0.
//  k2b: U = adj@Wh from bitmask via MFMA; dual row-set; depth-1 fragment
//       prefetch (R15-exact).
//  k3 : fused softmax + attention@U + ELU; factorized weights; ones-fragment
//       MFMA denominator; depth-1 fragment prefetch (R15-exact).
//
// Fragment convention (proven rounds 1/3/4/5):
//  element e of lane l <-> k = kblock*32 + (l>>4)*8 + e; A row / B col = l&15;
//  C/D: col = l&15, row = (l>>4)*4 + reg.
//  Bpack/Upack: frag[(kb*4+b)*64 + lane][e]  (s16x8 per lane)
// Mask bit (row i, col j): word ML[i*128 + (j>>8)*4 + (j&3)], bit (j>>2)&63.

#define N 8192

typedef float f32x4 __attribute__((ext_vector_type(4)));
typedef short s16x8 __attribute__((ext_vector_type(8)));
typedef unsigned long long u64;
typedef u64 u64x2 __attribute__((ext_vector_type(2)));

union PF { s16x8 v; unsigned u[4]; };

__device__ __forceinline__ unsigned short f2bf(float x) {
  unsigned u = __float_as_uint(x);
  u += 0x7FFFu + ((u >> 16) & 1u);   // RNE
  return (unsigned short)(u >> 16);
}
__device__ __forceinline__ unsigned pack2(unsigned short lo, unsigned short hi) {
  return (unsigned)lo | ((unsigned)hi << 16);
}
// round-half-up bf16 pair pack (2 ops/elem; wt small positive => safe)
__device__ __forceinline__ unsigned packrn(float lo, float hi) {
  return ((__float_as_uint(lo) + 0x8000u) >> 16) |
         ((__float_as_uint(hi) + 0x8000u) & 0xFFFF0000u);
}

#define MFMA __builtin_amdgcn_mfma_f32_16x16x32_bf16

// ---------------- kA: mask stream (LDS-staged, depth-2) + 2-row k1; 3 waves ----------------
__global__ __launch_bounds__(192) void kA(const float* __restrict__ adj,
                                          const float* __restrict__ h,
                                          const float* __restrict__ W,
                                          const float* __restrict__ a,
                                          u64* __restrict__ ML,
                                          unsigned short* __restrict__ Bpack,
                                          float* __restrict__ expg,
                                          float* __restrict__ expg2,
                                          float* __restrict__ Af,
                                          float* __restrict__ Cf,
                                          float* __restrict__ Enf) {
  __shared__ u64 mbuf[2][128];   // 2 KB: per-streaming-wave mask staging
  const int l = threadIdx.x & 63;
  const int w = threadIdx.x >> 6;
  const int bid = blockIdx.x;
  if (w < 2) {
    const int i = (bid << 1) + w;
    const float* ap = adj + (size_t)i * N + (l << 2);
    u64* mp = ML + (size_t)i * 128;
    f32x4 a0 = *(const f32x4*)(ap + (0 << 8));
    f32x4 a1 = *(const f32x4*)(ap + (1 << 8));
    f32x4 a2 = *(const f32x4*)(ap + (2 << 8));
    f32x4 a3 = *(const f32x4*)(ap + (3 << 8));
    f32x4 b0 = *(const f32x4*)(ap + (4 << 8));
    f32x4 b1 = *(const f32x4*)(ap + (5 << 8));
    f32x4 b2 = *(const f32x4*)(ap + (6 << 8));
    f32x4 b3 = *(const f32x4*)(ap + (7 << 8));
    for (int it = 0; it < 8; ++it) {
      const int gn = (it < 6) ? (it + 2) : it;   // tail: L2-hot reload
      f32x4 n0 = *(const f32x4*)(ap + (((gn << 2) + 0) << 8));
      f32x4 n1 = *(const f32x4*)(ap + (((gn << 2) + 1) << 8));
      f32x4 n2 = *(const f32x4*)(ap + (((gn << 2) + 2) << 8));
      f32x4 n3 = *(const f32x4*)(ap + (((gn << 2) + 3) << 8));
      u64 B0  = __ballot(a0.x > 0.f), B1  = __ballot(a0.y > 0.f);
      u64 B2  = __ballot(a0.z > 0.f), B3  = __ballot(a0.w > 0.f);
      u64 B4  = __ballot(a1.x > 0.f), B5  = __ballot(a1.y > 0.f);
      u64 B6  = __ballot(a1.z > 0.f), B7  = __ballot(a1.w > 0.f);
      u64 B8  = __ballot(a2.x > 0.f), B9  = __ballot(a2.y > 0.f);
      u64 B10 = __ballot(a2.z > 0.f), B11 = __ballot(a2.w > 0.f);
      u64 B12 = __ballot(a3.x > 0.f), B13 = __ballot(a3.y > 0.f);
      u64 B14 = __ballot(a3.z > 0.f), B15 = __ballot(a3.w > 0.f);
      if (l == 0) {
        u64x2* q = (u64x2*)&mbuf[w][it << 4];
        u64x2 t0; t0.x = B0;  t0.y = B1;  q[0] = t0;
        u64x2 t1; t1.x = B2;  t1.y = B3;  q[1] = t1;
        u64x2 t2; t2.x = B4;  t2.y = B5;  q[2] = t2;
        u64x2 t3; t3.x = B6;  t3.y = B7;  q[3] = t3;
        u64x2 t4; t4.x = B8;  t4.y = B9;  q[4] = t4;
        u64x2 t5; t5.x = B10; t5.y = B11; q[5] = t5;
        u64x2 t6; t6.x = B12; t6.y = B13; q[6] = t6;
        u64x2 t7; t7.x = B14; t7.y = B15; q[7] = t7;
      }
      a0 = b0; a1 = b1; a2 = b2; a3 = b3;
      b0 = n0; b1 = n1; b2 = n2; b3 = n3;
    }
    asm volatile("s_waitcnt lgkmcnt(0)" ::: "memory");
    u64x2 mv = *((const u64x2*)&mbuf[w][l << 1]);
    ((u64x2*)mp)[l] = mv;                      // one coalesced 1KB store/row
  } else {
    // ----- k1 role: 2 rows per wave, shared W loads -----
    const int i0r = bid << 1;
    const float* h0 = h + (size_t)i0r * 256;
    const float* h1 = h0 + 256;
    float acc0 = 0.f, acc1 = 0.f;
#pragma unroll 4
    for (int kb = 0; kb < 64; ++kb) {
      f32x4 hv0 = *(const f32x4*)(h0 + (kb << 2));
      f32x4 hv1 = *(const f32x4*)(h1 + (kb << 2));
      const float w0 = W[((kb << 2) + 0) * 64 + l];
      const float w1 = W[((kb << 2) + 1) * 64 + l];
      const float w2 = W[((kb << 2) + 2) * 64 + l];
      const float w3 = W[((kb << 2) + 3) * 64 + l];
      acc0 += hv0.x * w0; acc0 += hv0.y * w1;
      acc0 += hv0.z * w2; acc0 += hv0.w * w3;
      acc1 += hv1.x * w0; acc1 += hv1.y * w1;
      acc1 += hv1.z * w2; acc1 += hv1.w * w3;
    }
    const float al = a[l], bl = a[64 + l];
    float s10 = acc0 * al, s20 = acc0 * bl;
    float s11 = acc1 * al, s21 = acc1 * bl;
#pragma unroll
    for (int d = 32; d > 0; d >>= 1) {
      s10 += __shfl_xor(s10, d);
      s20 += __shfl_xor(s20, d);
      s11 += __shfl_xor(s11, d);
      s21 += __shfl_xor(s21, d);
    }
    if (l == 0) {
      expg[i0r]  = __expf(s20);
      expg2[i0r] = __expf(0.2f * s20);
      Af[i0r]    = __expf(s10);
      Cf[i0r]    = __expf(0.2f * s10);
      Enf[i0r]   = __expf(-s10);
      expg[i0r + 1]  = __expf(s21);
      expg2[i0r + 1] = __expf(0.2f * s21);
      Af[i0r + 1]    = __expf(s11);
      Cf[i0r + 1]    = __expf(0.2f * s11);
      Enf[i0r + 1]   = __expf(-s11);
    }
#pragma unroll
    for (int rr = 0; rr < 2; ++rr) {
      const int i = i0r + rr;
      const float acc = rr ? acc1 : acc0;
      const int kb = i >> 5;
      const int b = l >> 4;
      const int lp = (l & 15) | (((i >> 3) & 3) << 4);
      const int e = i & 7;
      Bpack[(((size_t)(kb * 4 + b)) * 64 + lp) * 8 + e] = f2bf(acc);
    }
  }
}

// ---------------- k2b: U from mask via MFMA, dual row-set, frag prefetch (R15) ----------------
__global__ __launch_bounds__(512) void k2b(const u64* __restrict__ ML,
                                           const unsigned short* __restrict__ Bpack,
                                           unsigned short* __restrict__ Upack) {
  __shared__ float red[2][8][64][16];   // 64 KB
  const int l = threadIdx.x & 63;
  const int w = threadIdx.x >> 6;
  const int i0 = blockIdx.x << 5;          // 32 rows/block
  const int r = l & 15, kg = l >> 4;
  const s16x8* Bv = (const s16x8*)Bpack;
  const u64x2* mrow0 = (const u64x2*)(ML + (size_t)(i0 + r) * 128);
  const u64x2* mrow1 = (const u64x2*)(ML + (size_t)(i0 + 16 + r) * 128);
  const int sh0 = kg << 1;
  f32x4 x0 = {0.f,0.f,0.f,0.f}, x1 = x0, x2 = x0, x3 = x0;
  f32x4 y0 = x0, y1 = x0, y2 = x0, y3 = x0;
  const int jb0 = w << 5;
  s16x8 c0, c1, c2, c3;
  {
    const size_t bi = ((size_t)jb0 << 8) + l;
    c0 = Bv[bi]; c1 = Bv[bi + 64]; c2 = Bv[bi + 128]; c3 = Bv[bi + 192];
  }
  for (int cc = 0; cc < 4; ++cc) {
    const int c = (w << 2) + cc;           // chunk of 256 cols
    u64x2 ma = mrow0[(c << 1)], mb = mrow0[(c << 1) + 1];
    const u64 xa0 = ma.x >> sh0, xa1 = ma.y >> sh0,
              xa2 = mb.x >> sh0, xa3 = mb.y >> sh0;
    u64x2 mc = mrow1[(c << 1)], md = mrow1[(c << 1) + 1];
    const u64 ya0 = mc.x >> sh0, ya1 = mc.y >> sh0,
              ya2 = md.x >> sh0, ya3 = md.y >> sh0;
#pragma unroll
    for (int j7 = 0; j7 < 8; ++j7) {
      const int jb = (c << 3) + j7;
      const int jbn = (cc == 3 && j7 == 7) ? jb : (jb + 1);
      const size_t bn = ((size_t)jbn << 8) + l;
      s16x8 n0 = Bv[bn], n1 = Bv[bn + 64], n2 = Bv[bn + 128], n3 = Bv[bn + 192];
      const unsigned p0 = (unsigned)(xa0 >> (j7 << 3)) & 1u;
      const unsigned p1 = (unsigned)(xa1 >> (j7 << 3)) & 1u;
      const unsigned p2 = (unsigned)(xa2 >> (j7 << 3)) & 1u;
      const unsigned p3 = (unsigned)(xa3 >> (j7 << 3)) & 1u;
      const unsigned p4 = (unsigned)(xa0 >> ((j7 << 3) + 1)) & 1u;
      const unsigned p5 = (unsigned)(xa1 >> ((j7 << 3) + 1)) & 1u;
      const unsigned p6 = (unsigned)(xa2 >> ((j7 << 3) + 1)) & 1u;
      const unsigned p7 = (unsigned)(xa3 >> ((j7 << 3) + 1)) & 1u;
      const unsigned q0 = (unsigned)(ya0 >> (j7 << 3)) & 1u;
      const unsigned q1 = (unsigned)(ya1 >> (j7 << 3)) & 1u;
      const unsigned q2 = (unsigned)(ya2 >> (j7 << 3)) & 1u;
      const unsigned q3 = (unsigned)(ya3 >> (j7 << 3)) & 1u;
      const unsigned q4 = (unsigned)(ya0 >> ((j7 << 3) + 1)) & 1u;
      const unsigned q5 = (unsigned)(ya1 >> ((j7 << 3) + 1)) & 1u;
      const unsigned q6 = (unsigned)(ya2 >> ((j7 << 3) + 1)) & 1u;
      const unsigned q7 = (unsigned)(ya3 >> ((j7 << 3) + 1)) & 1u;
      s16x8 af0, af1;
      af0[0] = p0 ? (short)0x3F80 : (short)0;
      af0[1] = p1 ? (short)0x3F80 : (short)0;
      af0[2] = p2 ? (short)0x3F80 : (short)0;
      af0[3] = p3 ? (short)0x3F80 : (short)0;
      af0[4] = p4 ? (short)0x3F80 : (short)0;
      af0[5] = p5 ? (short)0x3F80 : (short)0;
      af0[6] = p6 ? (short)0x3F80 : (short)0;
      af0[7] = p7 ? (short)0x3F80 : (short)0;
      af1[0] = q0 ? (short)0x3F80 : (short)0;
      af1[1] = q1 ? (short)0x3F80 : (short)0;
      af1[2] = q2 ? (short)0x3F80 : (short)0;
      af1[3] = q3 ? (short)0x3F80 : (short)0;
      af1[4] = q4 ? (short)0x3F80 : (short)0;
      af1[5] = q5 ? (short)0x3F80 : (short)0;
      af1[6] = q6 ? (short)0x3F80 : (short)0;
      af1[7] = q7 ? (short)0x3F80 : (short)0;
      x0 = MFMA(af0, c0, x0, 0, 0, 0);
      x1 = MFMA(af0, c1, x1, 0, 0, 0);
      x2 = MFMA(af0, c2, x2, 0, 0, 0);
      x3 = MFMA(af0, c3, x3, 0, 0, 0);
      y0 = MFMA(af1, c0, y0, 0, 0, 0);
      y1 = MFMA(af1, c1, y1, 0, 0, 0);
      y2 = MFMA(af1, c2, y2, 0, 0, 0);
      y3 = MFMA(af1, c3, y3, 0, 0, 0);
      c0 = n0; c1 = n1; c2 = n2; c3 = n3;
    }
  }
#pragma unroll
  for (int q = 0; q < 4; ++q) {
    red[0][w][l][q] = x0[q]; red[0][w][l][4 + q] = x1[q];
    red[0][w][l][8 + q] = x2[q]; red[0][w][l][12 + q] = x3[q];
    red[1][w][l][q] = y0[q]; red[1][w][l][4 + q] = y1[q];
    red[1][w][l][8 + q] = y2[q]; red[1][w][l][12 + q] = y3[q];
  }
  __syncthreads();
  const int tl = threadIdx.x & 63;
  const int b = (threadIdx.x >> 6) & 3;
  const int sE = threadIdx.x >> 8;
  const int reg0 = sE << 1;
#pragma unroll
  for (int s = 0; s < 2; ++s) {
    float u0 = 0.f, u1 = 0.f;
#pragma unroll
    for (int w8 = 0; w8 < 8; ++w8) {
      u0 += red[s][w8][tl][(b << 2) + reg0];
      u1 += red[s][w8][tl][(b << 2) + reg0 + 1];
    }
    const int k0 = i0 + (s << 4) + ((tl >> 4) << 2) + reg0;
    const unsigned pkv = pack2(f2bf(u0), f2bf(u1));
    const int kbD = k0 >> 5, lgrp = (k0 >> 3) & 3, e0 = k0 & 7;
    *(unsigned*)((char*)Upack +
        ((size_t)((kbD << 2) + b) * 64 + ((tl & 15) | (lgrp << 4))) * 16 + (e0 << 1)) = pkv;
  }
}

// ---------------- k3: fused softmax + attention@U + ELU, frag prefetch (R15) ----------------
__global__ __launch_bounds__(512) void k3(const u64* __restrict__ ML,
                                          const unsigned short* __restrict__ Upack,
                                          const float* __restrict__ expg,
                                          const float* __restrict__ expg2,
                                          const float* __restrict__ Af,
                                          const float* __restrict__ Cf,
                                          const float* __restrict__ Enf,
                                          float* __restrict__ out) {
  __shared__ float red[2][8][64][16];   // 64 KB
  __shared__ float wred[2][8][16];
  const int l = threadIdx.x & 63;
  const int w = threadIdx.x >> 6;
  const int i0 = blockIdx.x << 5;
  const int r = l & 15, kg = l >> 4;
  const float enf0 = Enf[i0 + r],      enf1 = Enf[i0 + 16 + r];
  const float Ar0 = Af[i0 + r],        Cr0 = Cf[i0 + r];
  const float Ar1 = Af[i0 + 16 + r],   Cr1 = Cf[i0 + 16 + r];
  const s16x8* Uv = (const s16x8*)Upack;
  const u64x2* mrow0 = (const u64x2*)(ML + (size_t)(i0 + r) * 128);
  const u64x2* mrow1 = (const u64x2*)(ML + (size_t)(i0 + 16 + r) * 128);
  const int sh0 = kg << 1;
  const s16x8 ones = {(short)0x3F80, (short)0x3F80, (short)0x3F80, (short)0x3F80,
                      (short)0x3F80, (short)0x3F80, (short)0x3F80, (short)0x3F80};
  f32x4 x0 = {0.f,0.f,0.f,0.f}, x1 = x0, x2 = x0, x3 = x0, xd = x0;
  f32x4 y0 = x0, y1 = x0, y2 = x0, y3 = x0, yd = x0;
  const int jb0 = w << 5;
  s16x8 c0, c1, c2, c3;
  {
    const size_t bi = ((size_t)jb0 << 8) + l;
    c0 = Uv[bi]; c1 = Uv[bi + 64]; c2 = Uv[bi + 128]; c3 = Uv[bi + 192];
  }
  for (int cc = 0; cc < 4; ++cc) {
    const int c = (w << 2) + cc;
    u64x2 ma = mrow0[(c << 1)], mb = mrow0[(c << 1) + 1];
    const u64 xa0 = ma.x >> sh0, xa1 = ma.y >> sh0,
              xa2 = mb.x >> sh0, xa3 = mb.y >> sh0;
    u64x2 mc = mrow1[(c << 1)], md = mrow1[(c << 1) + 1];
    const u64 ya0 = mc.x >> sh0, ya1 = mc.y >> sh0,
              ya2 = md.x >> sh0, ya3 = md.y >> sh0;
#pragma unroll
    for (int j7 = 0; j7 < 8; ++j7) {
      const int jb = (c << 3) + j7;
      const int jbn = (cc == 3 && j7 == 7) ? jb : (jb + 1);
      const size_t bn = ((size_t)jbn << 8) + l;
      s16x8 n0 = Uv[bn], n1 = Uv[bn + 64], n2 = Uv[bn + 128], n3 = Uv[bn + 192];
      f32x4 eg0 = *(const f32x4*)(expg + (jb << 5) + (kg << 3));
      f32x4 eg1 = *(const f32x4*)(expg + (jb << 5) + (kg << 3) + 4);
      f32x4 eh0 = *(const f32x4*)(expg2 + (jb << 5) + (kg << 3));
      f32x4 eh1 = *(const f32x4*)(expg2 + (jb << 5) + (kg << 3) + 4);
#define WT(wq, sh, egv, ehv, enf, Ar, Cr)                                    \
      ((((wq) >> (sh)) & 1ull) ?                                             \
        (((egv) > (enf)) ? (Ar) * (egv) : (Cr) * (ehv)) : 0.f)
      const float w00 = WT(xa0, (j7 << 3),     eg0.x, eh0.x, enf0, Ar0, Cr0);
      const float w01 = WT(xa1, (j7 << 3),     eg0.y, eh0.y, enf0, Ar0, Cr0);
      const float w02 = WT(xa2, (j7 << 3),     eg0.z, eh0.z, enf0, Ar0, Cr0);
      const float w03 = WT(xa3, (j7 << 3),     eg0.w, eh0.w, enf0, Ar0, Cr0);
      const float w04 = WT(xa0, (j7 << 3) + 1, eg1.x, eh1.x, enf0, Ar0, Cr0);
      const float w05 = WT(xa1, (j7 << 3) + 1, eg1.y, eh1.y, enf0, Ar0, Cr0);
      const float w06 = WT(xa2, (j7 << 3) + 1, eg1.z, eh1.z, enf0, Ar0, Cr0);
      const float w07 = WT(xa3, (j7 << 3) + 1, eg1.w, eh1.w, enf0, Ar0, Cr0);
      const float w10 = WT(ya0, (j7 << 3),     eg0.x, eh0.x, enf1, Ar1, Cr1);
      const float w11 = WT(ya1, (j7 << 3),     eg0.y, eh0.y, enf1, Ar1, Cr1);
      const float w12 = WT(ya2, (j7 << 3),     eg0.z, eh0.z, enf1, Ar1, Cr1);
      const float w13 = WT(ya3, (j7 << 3),     eg0.w, eh0.w, enf1, Ar1, Cr1);
      const float w14 = WT(ya0, (j7 << 3) + 1, eg1.x, eh1.x, enf1, Ar1, Cr1);
      const float w15 = WT(ya1, (j7 << 3) + 1, eg1.y, eh1.y, enf1, Ar1, Cr1);
      const float w16 = WT(ya2, (j7 << 3) + 1, eg1.z, eh1.z, enf1, Ar1, Cr1);
      const float w17 = WT(ya3, (j7 << 3) + 1, eg1.w, eh1.w, enf1, Ar1, Cr1);
#undef WT
      PF pf0, pf1;
      pf0.u[0] = packrn(w00, w01); pf0.u[1] = packrn(w02, w03);
      pf0.u[2] = packrn(w04, w05); pf0.u[3] = packrn(w06, w07);
      pf1.u[0] = packrn(w10, w11); pf1.u[1] = packrn(w12, w13);
      pf1.u[2] = packrn(w14, w15); pf1.u[3] = packrn(w16, w17);
      x0 = MFMA(pf0.v, c0, x0, 0, 0, 0);
      x1 = MFMA(pf0.v, c1, x1, 0, 0, 0);
      x2 = MFMA(pf0.v, c2, x2, 0, 0, 0);
      x3 = MFMA(pf0.v, c3, x3, 0, 0, 0);
      xd = MFMA(pf0.v, ones, xd, 0, 0, 0);
      y0 = MFMA(pf1.v, c0, y0, 0, 0, 0);
      y1 = MFMA(pf1.v, c1, y1, 0, 0, 0);
      y2 = MFMA(pf1.v, c2, y2, 0, 0, 0);
      y3 = MFMA(pf1.v, c3, y3, 0, 0, 0);
      yd = MFMA(pf1.v, ones, yd, 0, 0, 0);
      c0 = n0; c1 = n1; c2 = n2; c3 = n3;
    }
  }
  if (r == 0) {
#pragma unroll
    for (int q = 0; q < 4; ++q) {
      wred[0][w][(kg << 2) + q] = xd[q];   // rowsum (all cols of ones-D equal)
      wred[1][w][(kg << 2) + q] = yd[q];
    }
  }
#pragma unroll
  for (int q = 0; q < 4; ++q) {
    red[0][w][l][q] = x0[q]; red[0][w][l][4 + q] = x1[q];
    red[0][w][l][8 + q] = x2[q]; red[0][w][l][12 + q] = x3[q];
    red[1][w][l][q] = y0[q]; red[1][w][l][4 + q] = y1[q];
    red[1][w][l][8 + q] = y2[q]; red[1][w][l][12 + q] = y3[q];
  }
  __syncthreads();
  const int tl = threadIdx.x & 63;
  const int b = (threadIdx.x >> 6) & 3;
  const int sE = threadIdx.x >> 8;
#pragma unroll
  for (int s = 0; s < 2; ++s) {
#pragma unroll
    for (int q = 0; q < 2; ++q) {
      const int reg = (sE << 1) + q;
      const int idx = (b << 2) + reg;
      const int row = ((tl >> 4) << 2) + reg;
      float sv = 0.f, dv = 0.f;
#pragma unroll
      for (int w8 = 0; w8 < 8; ++w8) {
        sv += red[s][w8][tl][idx];
        dv += wred[s][w8][row];
      }
      dv = (dv > 0.f) ? dv : 1.f;            // defensive: avoid 0/0
      float v = sv / dv;
      v = (v > 0.f) ? v : (__expf(v) - 1.f); // ELU
      out[(size_t)(i0 + (s << 4) + row) * 64 + (b << 4) + (tl & 15)] = v;
    }
  }
}

extern "C" void kernel_launch(void* const* d_in, const int* in_sizes, int n_in,
                              void* d_out, int out_size, void* d_ws, size_t ws_size,
                              hipStream_t stream) {
  const float* h   = (const float*)d_in[0];
  const float* adj = (const float*)d_in[1];
  const float* W   = (const float*)d_in[2];
  const float* a   = (const float*)d_in[3];
  float* out = (float*)d_out;
  char* ws = (char*)d_ws;
  unsigned short* Bpack = (unsigned short*)(ws);                   // 1 MB
  unsigned short* Upack = (unsigned short*)(ws + (1u << 20));      // 1 MB
  float* expg  = (float*)(ws + (2u << 20));                        // 32 KB
  float* expg2 = (float*)(ws + (2u << 20) + 1u * 32768u);          // 32 KB
  float* Af    = (float*)(ws + (2u << 20) + 2u * 32768u);          // 32 KB
  float* Cf    = (float*)(ws + (2u << 20) + 3u * 32768u);          // 32 KB
  float* Enf   = (float*)(ws + (2u << 20) + 4u * 32768u);          // 32 KB
  u64* ML = (u64*)(ws + (3u << 20));                               // 8 MB

  hipLaunchKernelGGL(kA,  dim3(4096), dim3(192), 0, stream,
                     adj, h, W, a, ML, Bpack, expg, expg2, Af, Cf, Enf);
  hipLaunchKernelGGL(k2b, dim3(256), dim3(512), 0, stream,
                     ML, Bpack, Upack);
  hipLaunchKernelGGL(k3,  dim3(256), dim3(512), 0, stream,
                     ML, Upack, expg, expg2, Af, Cf, Enf, out);
}